// Round 4
// baseline (402.589 us; speedup 1.0000x reference)
//
#include <hip/hip_runtime.h>
#include <hip/hip_bf16.h>
#include <stdint.h>

#define DM 1024
#define DKH 64
#define NH 16
#define NB 4
#define SEQ 2048

typedef __attribute__((ext_vector_type(8))) short bf16x8;
typedef __attribute__((ext_vector_type(8))) unsigned short ushort8;
typedef __attribute__((ext_vector_type(4))) float f32x4;

__device__ inline unsigned short f2bf(float f) {
  union { float f; unsigned u; } c; c.f = f;
  unsigned u = c.u;
  u += 0x7fff + ((u >> 16) & 1);   // round-to-nearest-even
  return (unsigned short)(u >> 16);
}

// forced (un-sinkable) 16B global load
__device__ inline bf16x8 gload16(const unsigned short* p) {
  bf16x8 r;
  asm volatile("global_load_dwordx4 %0, %1, off" : "=v"(r) : "v"(p));
  return r;
}

#define WAITV(N)                                            \
  do {                                                      \
    asm volatile("s_waitcnt vmcnt(" #N ")" ::: "memory");   \
    __builtin_amdgcn_sched_barrier(0);                      \
  } while (0)

// ---------- weight transpose + cast: Wt[n][k] = bf16(W[k][n]), 1024x1024 ----------
__global__ __launch_bounds__(256) void wcast_t(const float* __restrict__ W,
                                               unsigned short* __restrict__ Wt) {
  __shared__ float tile[32][33];
  int bk = blockIdx.x * 32, bn = blockIdx.y * 32;
  int tx = threadIdx.x & 31, ty = threadIdx.x >> 5;  // ty 0..7
#pragma unroll
  for (int i = 0; i < 4; ++i)
    tile[ty + 8 * i][tx] = W[(size_t)(bk + ty + 8 * i) * DM + bn + tx];
  __syncthreads();
#pragma unroll
  for (int i = 0; i < 4; ++i)
    Wt[(size_t)(bn + ty + 8 * i) * DM + bk + tx] = f2bf(tile[tx][ty + 8 * i]);
}

// ---------- 128x128 tile bf16 GEMM, M=8192 N=1024 K=1024 ----------
template <int EPI, int ABF16>
__global__ __launch_bounds__(256) void gemm128(const void* __restrict__ Av,
                                               const unsigned short* __restrict__ Bt,
                                               const float* __restrict__ bias,
                                               void* __restrict__ Cv, float scale) {
  __shared__ __align__(16) unsigned short As[128][32];
  __shared__ __align__(16) unsigned short Bs[128][32];
  const int K = DM;
  int t = threadIdx.x;
  int wave = t >> 6, lane = t & 63;
  int wr = wave >> 1, wc = wave & 1;
  int l15 = lane & 15, g = lane >> 4;
  int tm = blockIdx.x >> 3, tn = blockIdx.x & 7;  // N/128 = 8
  int rowBase = tm * 128, colBase = tn * 128;

  f32x4 acc[4][4];
#pragma unroll
  for (int mi = 0; mi < 4; ++mi)
#pragma unroll
    for (int ni = 0; ni < 4; ++ni) acc[mi][ni] = (f32x4){0.f, 0.f, 0.f, 0.f};

  int srow = t >> 2;        // 0..63
  int skb = (t & 3) * 8;    // 0,8,16,24

  for (int kt = 0; kt < K; kt += 32) {
    __syncthreads();
#pragma unroll
    for (int i = 0; i < 2; ++i) {
      int row = srow + i * 64;
      if (ABF16) {
        ushort8 v = *reinterpret_cast<const ushort8*>(
            (const unsigned short*)Av + (size_t)(rowBase + row) * K + kt + skb);
        *reinterpret_cast<ushort8*>(&As[row][skb]) = v;
      } else {
        const float* Af = (const float*)Av + (size_t)(rowBase + row) * K + kt + skb;
        float4 x = *reinterpret_cast<const float4*>(Af);
        float4 y = *reinterpret_cast<const float4*>(Af + 4);
        ushort8 v;
        v[0] = f2bf(x.x); v[1] = f2bf(x.y); v[2] = f2bf(x.z); v[3] = f2bf(x.w);
        v[4] = f2bf(y.x); v[5] = f2bf(y.y); v[6] = f2bf(y.z); v[7] = f2bf(y.w);
        *reinterpret_cast<ushort8*>(&As[row][skb]) = v;
      }
      ushort8 w = *reinterpret_cast<const ushort8*>(
          Bt + (size_t)(colBase + row) * K + kt + skb);
      *reinterpret_cast<ushort8*>(&Bs[row][skb]) = w;
    }
    __syncthreads();

    bf16x8 af[4], bfr[4];
#pragma unroll
    for (int mi = 0; mi < 4; ++mi)
      af[mi] = *reinterpret_cast<const bf16x8*>(&As[wr * 64 + mi * 16 + l15][g * 8]);
#pragma unroll
    for (int ni = 0; ni < 4; ++ni)
      bfr[ni] = *reinterpret_cast<const bf16x8*>(&Bs[wc * 64 + ni * 16 + l15][g * 8]);
#pragma unroll
    for (int mi = 0; mi < 4; ++mi)
#pragma unroll
      for (int ni = 0; ni < 4; ++ni)
        acc[mi][ni] = __builtin_amdgcn_mfma_f32_16x16x32_bf16(af[mi], bfr[ni],
                                                              acc[mi][ni], 0, 0, 0);
  }

#pragma unroll
  for (int ni = 0; ni < 4; ++ni) {
    int col = colBase + wc * 64 + ni * 16 + l15;
    float bv = bias[col];
#pragma unroll
    for (int mi = 0; mi < 4; ++mi) {
#pragma unroll
      for (int r = 0; r < 4; ++r) {
        int row = rowBase + wr * 64 + mi * 16 + g * 4 + r;
        float val = (acc[mi][ni][r] + bv) * scale;
        if (EPI == 0) {
          int b_ = row >> 11, s_ = row & 2047;
          int h_ = col >> 6, d_ = col & 63;
          ((unsigned short*)Cv)[(size_t)((b_ * NH + h_) * SEQ + s_) * DKH + d_] = f2bf(val);
        } else if (EPI == 1) {
          int b_ = row >> 11, s_ = row & 2047;
          int h_ = col >> 6, d_ = col & 63;
          ((unsigned short*)Cv)[(size_t)((b_ * NH + h_) * DKH + d_) * SEQ + s_] = f2bf(val);
        } else {
          ((float*)Cv)[(size_t)row * DM + col] = val;
        }
      }
    }
  }
}

// ---------- flash attention (swapped QK^T, asm-prefetch pipeline, XCD swizzle) ----
// Q,K [BH][S][64] bf16 (Q pre-scaled by 0.125*log2e), Vt [BH][64][S] bf16,
// AO [B][S][H*64] bf16.  Per wave: 32 q-rows (2 x 16-row fragments).
// K/V double-buffered in registers via asm global_load_dwordx4 + counted vmcnt.
__global__ __launch_bounds__(256) void attn_fwd(const unsigned short* __restrict__ Qb,
                                                const unsigned short* __restrict__ Kb,
                                                const unsigned short* __restrict__ Vt,
                                                unsigned short* __restrict__ AO) {
  __shared__ __align__(16) unsigned short Plds[4][2][16][40];
  int t = threadIdx.x;
  int wave = t >> 6, lane = t & 63;
  int l15 = lane & 15, g = lane >> 4;
  // XCD swizzle: all 16 qtiles of one bh land on one XCD (bid % 8 = XCD).
  int bid = blockIdx.x;                 // 0..1023
  int xcd = bid & 7, j = bid >> 3;      // j 0..127
  int bh = (xcd << 3) | (j >> 4);       // 0..63
  int qtile = j & 15;                   // 0..15
  const size_t baseQK = (size_t)bh * SEQ * DKH;
  const size_t baseV = (size_t)bh * DKH * SEQ;
  int q0 = qtile * 128 + wave * 32;

  bf16x8 aQ[2][2];
#pragma unroll
  for (int qf = 0; qf < 2; ++qf)
#pragma unroll
    for (int dh = 0; dh < 2; ++dh)
      aQ[qf][dh] = *reinterpret_cast<const bf16x8*>(
          Qb + baseQK + (size_t)(q0 + qf * 16 + l15) * DKH + dh * 32 + g * 8);

  float m[2] = {-1e30f, -1e30f}, lsum[2] = {0.f, 0.f};
  f32x4 accO[2][4];
#pragma unroll
  for (int qf = 0; qf < 2; ++qf)
#pragma unroll
    for (int dt = 0; dt < 4; ++dt) accO[qf][dt] = (f32x4){0.f, 0.f, 0.f, 0.f};

  // per-lane streaming pointers
  const unsigned short* kp0 = Kb + baseQK + (size_t)l15 * DKH + g * 8;  // tt0 dh0
  const unsigned short* kp1 = kp0 + 32;                                 // tt0 dh1
  const unsigned short* kp2 = kp0 + 16 * DKH;                           // tt1 dh0
  const unsigned short* kp3 = kp2 + 32;                                 // tt1 dh1
  const unsigned short* vp0 = Vt + baseV + (size_t)l15 * SEQ + g * 8;   // dt0
  const unsigned short* vp1 = vp0 + 16 * SEQ;
  const unsigned short* vp2 = vp0 + 32 * SEQ;
  const unsigned short* vp3 = vp0 + 48 * SEQ;

  bf16x8 kA[2][2], kB[2][2], vA[4], vB[4];

#define ISSUE_K(buf)                                                     \
  do {                                                                   \
    buf[0][0] = gload16(kp0); buf[0][1] = gload16(kp1);                  \
    buf[1][0] = gload16(kp2); buf[1][1] = gload16(kp3);                  \
    kp0 += 32 * DKH; kp1 += 32 * DKH; kp2 += 32 * DKH; kp3 += 32 * DKH;  \
  } while (0)
#define ISSUE_V(buf)                                                     \
  do {                                                                   \
    buf[0] = gload16(vp0); buf[1] = gload16(vp1);                        \
    buf[2] = gload16(vp2); buf[3] = gload16(vp3);                        \
    vp0 += 32; vp1 += 32; vp2 += 32; vp3 += 32;                          \
  } while (0)

  auto step = [&](const bf16x8 (&kf)[2][2], const bf16x8 (&vf)[4]) {
    f32x4 sc[2][2];
#pragma unroll
    for (int qf = 0; qf < 2; ++qf)
#pragma unroll
      for (int tt = 0; tt < 2; ++tt) {
        f32x4 z = (f32x4){0.f, 0.f, 0.f, 0.f};
#pragma unroll
        for (int dh = 0; dh < 2; ++dh)
          z = __builtin_amdgcn_mfma_f32_16x16x32_bf16(kf[tt][dh], aQ[qf][dh], z, 0, 0, 0);
        sc[qf][tt] = z;
      }
#pragma unroll
    for (int qf = 0; qf < 2; ++qf) {
      float vm = fmaxf(
          fmaxf(fmaxf(sc[qf][0][0], sc[qf][0][1]), fmaxf(sc[qf][0][2], sc[qf][0][3])),
          fmaxf(fmaxf(sc[qf][1][0], sc[qf][1][1]), fmaxf(sc[qf][1][2], sc[qf][1][3])));
      vm = fmaxf(vm, __shfl_xor(vm, 16));
      vm = fmaxf(vm, __shfl_xor(vm, 32));  // row-max of q=l15, uniform across g
      if (__any(vm > m[qf] + 8.f)) {       // defer-max (T13)
        float mnew = fmaxf(m[qf], vm);
        float alpha = __builtin_amdgcn_exp2f(m[qf] - mnew);
        m[qf] = mnew;
        lsum[qf] *= alpha;
        float ar[4];
#pragma unroll
        for (int r = 0; r < 4; ++r) ar[r] = __shfl(alpha, g * 4 + r);
#pragma unroll
        for (int dt = 0; dt < 4; ++dt)
#pragma unroll
          for (int r = 0; r < 4; ++r) accO[qf][dt][r] *= ar[r];
      }
      float pv[8];
#pragma unroll
      for (int tt = 0; tt < 2; ++tt)
#pragma unroll
        for (int r = 0; r < 4; ++r)
          pv[tt * 4 + r] = __builtin_amdgcn_exp2f(sc[qf][tt][r] - m[qf]);
      lsum[qf] +=
          ((pv[0] + pv[1]) + (pv[2] + pv[3])) + ((pv[4] + pv[5]) + (pv[6] + pv[7]));
#pragma unroll
      for (int tt = 0; tt < 2; ++tt)
#pragma unroll
        for (int s = 0; s < 2; ++s) {
          unsigned w;
          asm("v_cvt_pk_bf16_f32 %0, %1, %2"
              : "=v"(w)
              : "v"(pv[tt * 4 + 2 * s]), "v"(pv[tt * 4 + 2 * s + 1]));
          *reinterpret_cast<unsigned*>(&Plds[wave][qf][l15][tt * 16 + g * 4 + 2 * s]) = w;
        }
    }
    asm volatile("s_waitcnt lgkmcnt(0)" ::: "memory");
    __builtin_amdgcn_sched_barrier(0);
#pragma unroll
    for (int qf = 0; qf < 2; ++qf) {
      bf16x8 aP = *reinterpret_cast<const bf16x8*>(&Plds[wave][qf][l15][g * 8]);
#pragma unroll
      for (int dt = 0; dt < 4; ++dt)
        accO[qf][dt] =
            __builtin_amdgcn_mfma_f32_16x16x32_bf16(aP, vf[dt], accO[qf][dt], 0, 0, 0);
    }
  };

  const int NT = SEQ / 32;  // 64 chunks
  ISSUE_K(kA);
  ISSUE_V(vA);
  for (int pc = 0; pc < NT; pc += 2) {
    ISSUE_K(kB);
    ISSUE_V(vB);
    WAITV(8);        // chunk pc resident
    step(kA, vA);
    if (pc + 2 < NT) {
      ISSUE_K(kA);
      ISSUE_V(vA);
      WAITV(8);      // chunk pc+1 resident
    } else {
      WAITV(0);
    }
    step(kB, vB);
  }
#undef ISSUE_K
#undef ISSUE_V

  int b_ = bh >> 4, h_ = bh & 15;
#pragma unroll
  for (int qf = 0; qf < 2; ++qf) {
    float ls = lsum[qf];
    ls += __shfl_xor(ls, 16);
    ls += __shfl_xor(ls, 32);
#pragma unroll
    for (int r = 0; r < 4; ++r) {
      float lr = __shfl(ls, g * 4 + r);
      float inv = 1.f / lr;
      int sq = q0 + qf * 16 + g * 4 + r;
#pragma unroll
      for (int dt = 0; dt < 4; ++dt) {
        float val = accO[qf][dt][r] * inv;
        AO[(size_t)(b_ * SEQ + sq) * DM + h_ * DKH + dt * 16 + l15] = f2bf(val);
      }
    }
  }
}

extern "C" void kernel_launch(void* const* d_in, const int* in_sizes, int n_in,
                              void* d_out, int out_size, void* d_ws, size_t ws_size,
                              hipStream_t stream) {
  (void)in_sizes; (void)n_in; (void)out_size; (void)ws_size;
  const float* queries = (const float*)d_in[0];
  const float* keys = (const float*)d_in[1];
  const float* values = (const float*)d_in[2];
  const float* Wq = (const float*)d_in[3];
  const float* bq = (const float*)d_in[4];
  const float* Wk = (const float*)d_in[5];
  const float* bk = (const float*)d_in[6];
  const float* Wv = (const float*)d_in[7];
  const float* bv = (const float*)d_in[8];
  const float* Wo = (const float*)d_in[9];
  const float* bo = (const float*)d_in[10];
  float* out = (float*)d_out;

  char* ws = (char*)d_ws;
  unsigned short* wt_q = (unsigned short*)(ws + 0 * (1u << 21));
  unsigned short* wt_k = (unsigned short*)(ws + 1 * (1u << 21));
  unsigned short* wt_v = (unsigned short*)(ws + 2 * (1u << 21));
  unsigned short* wt_o = (unsigned short*)(ws + 3 * (1u << 21));
  unsigned short* Qb = (unsigned short*)(ws + (8u << 20));
  unsigned short* Kb = (unsigned short*)(ws + (24u << 20));
  unsigned short* Vt = (unsigned short*)(ws + (40u << 20));
  unsigned short* AO = (unsigned short*)(ws + (56u << 20));
  // total ws use: 72 MiB

  dim3 tgrid(32, 32);
  wcast_t<<<tgrid, 256, 0, stream>>>(Wq, wt_q);
  wcast_t<<<tgrid, 256, 0, stream>>>(Wk, wt_k);
  wcast_t<<<tgrid, 256, 0, stream>>>(Wv, wt_v);
  wcast_t<<<tgrid, 256, 0, stream>>>(Wo, wt_o);

  const float SQ = 0.125f * 1.4426950408889634f;  // fold 1/sqrt(64) and log2(e) into Q
  gemm128<0, 0><<<512, 256, 0, stream>>>(queries, wt_q, bq, Qb, SQ);
  gemm128<0, 0><<<512, 256, 0, stream>>>(keys, wt_k, bk, Kb, 1.0f);
  gemm128<1, 0><<<512, 256, 0, stream>>>(values, wt_v, bv, Vt, 1.0f);
  attn_fwd<<<1024, 256, 0, stream>>>(Qb, Kb, Vt, AO);
  gemm128<2, 1><<<512, 256, 0, stream>>>(AO, wt_o, bo, out, 1.0f);
}

// Round 5
// 397.803 us; speedup vs baseline: 1.0120x; 1.0120x over previous
//
#include <hip/hip_runtime.h>
#include <hip/hip_bf16.h>
#include <stdint.h>

#define DM 1024
#define DKH 64
#define NH 16
#define NB 4
#define SEQ 2048

typedef __attribute__((ext_vector_type(8))) short bf16x8;
typedef __attribute__((ext_vector_type(4))) short bf16x4;
typedef __attribute__((ext_vector_type(8))) unsigned short ushort8;
typedef __attribute__((ext_vector_type(4))) float f32x4;

__device__ inline unsigned short f2bf(float f) {
  union { float f; unsigned u; } c; c.f = f;
  unsigned u = c.u;
  u += 0x7fff + ((u >> 16) & 1);   // round-to-nearest-even
  return (unsigned short)(u >> 16);
}

// forced (un-sinkable) global loads with literal byte offsets
#define GLOAD16(dst, ptr, OFF)                                              \
  asm volatile("global_load_dwordx4 %0, %1, off offset:" #OFF               \
               : "=v"(dst) : "v"(ptr))
#define GLOAD8(dst, ptr, OFF)                                               \
  asm volatile("global_load_dwordx2 %0, %1, off offset:" #OFF               \
               : "=v"(dst) : "v"(ptr))

#define WAITV(N)                                            \
  do {                                                      \
    asm volatile("s_waitcnt vmcnt(" #N ")" ::: "memory");   \
    __builtin_amdgcn_sched_barrier(0);                      \
  } while (0)

// PV matrix op: D/C = acc (4 VGPR), A = V-frag (4 bf16), B = P-frag (4 bf16)
__device__ inline void mfma16x16x16(f32x4& acc, bf16x4 a, bf16x4 b) {
  asm("v_mfma_f32_16x16x16_bf16 %0, %1, %2, %0" : "+v"(acc) : "v"(a), "v"(b));
}

// ---------- weight transpose + cast: Wt[n][k] = bf16(W[k][n]), 1024x1024 ----------
__global__ __launch_bounds__(256) void wcast_t(const float* __restrict__ W,
                                               unsigned short* __restrict__ Wt) {
  __shared__ float tile[32][33];
  int bk = blockIdx.x * 32, bn = blockIdx.y * 32;
  int tx = threadIdx.x & 31, ty = threadIdx.x >> 5;  // ty 0..7
#pragma unroll
  for (int i = 0; i < 4; ++i)
    tile[ty + 8 * i][tx] = W[(size_t)(bk + ty + 8 * i) * DM + bn + tx];
  __syncthreads();
#pragma unroll
  for (int i = 0; i < 4; ++i)
    Wt[(size_t)(bn + ty + 8 * i) * DM + bk + tx] = f2bf(tile[tx][ty + 8 * i]);
}

// ---------- 128x128 tile bf16 GEMM, M=8192 N=1024 K=1024 ----------
// EPI: 0 = bf16 out, [B,H,S,64] (Q/K); 1 = bf16 out, chunk-major V^T
//      [BH][s/32][64][32]; 2 = fp32 out row-major.
template <int EPI, int ABF16>
__global__ __launch_bounds__(256) void gemm128(const void* __restrict__ Av,
                                               const unsigned short* __restrict__ Bt,
                                               const float* __restrict__ bias,
                                               void* __restrict__ Cv, float scale) {
  __shared__ __align__(16) unsigned short As[128][32];
  __shared__ __align__(16) unsigned short Bs[128][32];
  const int K = DM;
  int t = threadIdx.x;
  int wave = t >> 6, lane = t & 63;
  int wr = wave >> 1, wc = wave & 1;
  int l15 = lane & 15, g = lane >> 4;
  int tm = blockIdx.x >> 3, tn = blockIdx.x & 7;  // N/128 = 8
  int rowBase = tm * 128, colBase = tn * 128;

  f32x4 acc[4][4];
#pragma unroll
  for (int mi = 0; mi < 4; ++mi)
#pragma unroll
    for (int ni = 0; ni < 4; ++ni) acc[mi][ni] = (f32x4){0.f, 0.f, 0.f, 0.f};

  int srow = t >> 2;        // 0..63
  int skb = (t & 3) * 8;    // 0,8,16,24

  for (int kt = 0; kt < K; kt += 32) {
    __syncthreads();
#pragma unroll
    for (int i = 0; i < 2; ++i) {
      int row = srow + i * 64;
      if (ABF16) {
        ushort8 v = *reinterpret_cast<const ushort8*>(
            (const unsigned short*)Av + (size_t)(rowBase + row) * K + kt + skb);
        *reinterpret_cast<ushort8*>(&As[row][skb]) = v;
      } else {
        const float* Af = (const float*)Av + (size_t)(rowBase + row) * K + kt + skb;
        float4 x = *reinterpret_cast<const float4*>(Af);
        float4 y = *reinterpret_cast<const float4*>(Af + 4);
        ushort8 v;
        v[0] = f2bf(x.x); v[1] = f2bf(x.y); v[2] = f2bf(x.z); v[3] = f2bf(x.w);
        v[4] = f2bf(y.x); v[5] = f2bf(y.y); v[6] = f2bf(y.z); v[7] = f2bf(y.w);
        *reinterpret_cast<ushort8*>(&As[row][skb]) = v;
      }
      ushort8 w = *reinterpret_cast<const ushort8*>(
          Bt + (size_t)(colBase + row) * K + kt + skb);
      *reinterpret_cast<ushort8*>(&Bs[row][skb]) = w;
    }
    __syncthreads();

    bf16x8 af[4], bfr[4];
#pragma unroll
    for (int mi = 0; mi < 4; ++mi)
      af[mi] = *reinterpret_cast<const bf16x8*>(&As[wr * 64 + mi * 16 + l15][g * 8]);
#pragma unroll
    for (int ni = 0; ni < 4; ++ni)
      bfr[ni] = *reinterpret_cast<const bf16x8*>(&Bs[wc * 64 + ni * 16 + l15][g * 8]);
#pragma unroll
    for (int mi = 0; mi < 4; ++mi)
#pragma unroll
      for (int ni = 0; ni < 4; ++ni)
        acc[mi][ni] = __builtin_amdgcn_mfma_f32_16x16x32_bf16(af[mi], bfr[ni],
                                                              acc[mi][ni], 0, 0, 0);
  }

#pragma unroll
  for (int ni = 0; ni < 4; ++ni) {
    int col = colBase + wc * 64 + ni * 16 + l15;
    float bv = bias[col];
#pragma unroll
    for (int mi = 0; mi < 4; ++mi) {
#pragma unroll
      for (int r = 0; r < 4; ++r) {
        int row = rowBase + wr * 64 + mi * 16 + g * 4 + r;
        float val = (acc[mi][ni][r] + bv) * scale;
        if (EPI == 0) {
          int b_ = row >> 11, s_ = row & 2047;
          int h_ = col >> 6, d_ = col & 63;
          ((unsigned short*)Cv)[(size_t)((b_ * NH + h_) * SEQ + s_) * DKH + d_] = f2bf(val);
        } else if (EPI == 1) {
          int b_ = row >> 11, s_ = row & 2047;
          int h_ = col >> 6, d_ = col & 63;
          // chunk-major V^T: [bh][s/32][d=64][s%32]
          ((unsigned short*)Cv)[(size_t)(b_ * NH + h_) * (DKH * SEQ) +
                                (size_t)(s_ >> 5) * 2048 + d_ * 32 + (s_ & 31)] = f2bf(val);
        } else {
          ((float*)Cv)[(size_t)row * DM + col] = val;
        }
      }
    }
  }
}

// ---------- flash attention: ZERO-LDS inner loop ----------
// Swapped QK^T (mfma_16x16x32): lane(g,l15) holds P[q=l15][k=tt*16+g*4+r].
// That IS the B-operand layout of mfma_f32_16x16x16_bf16, so PV consumes P
// in-register: O^T[d][q] += V^T-frag(A) x P-frag(B). No LDS, no shuffles in
// the common path; softmax max/rescale/normalize are lane-local (cols = q = l15).
// Qb,Kb: [BH][S][64] bf16 (Q pre-scaled by 0.125*log2e); VtC: [BH][S/32][64][32];
// AO: [B][S][H*64] bf16.
__global__ __launch_bounds__(256) void attn_fwd(const unsigned short* __restrict__ Qb,
                                                const unsigned short* __restrict__ Kb,
                                                const unsigned short* __restrict__ VtC,
                                                unsigned short* __restrict__ AO) {
  int t = threadIdx.x;
  int wave = t >> 6, lane = t & 63;
  int l15 = lane & 15, g = lane >> 4;
  // XCD swizzle: all 16 qtiles of one bh land on one XCD (bid % 8 = XCD).
  int bid = blockIdx.x;                 // 0..1023
  int xcd = bid & 7, j = bid >> 3;      // j 0..127
  int bh = (xcd << 3) | (j >> 4);       // 0..63
  int qtile = j & 15;                   // 0..15
  const size_t baseQK = (size_t)bh * SEQ * DKH;
  const size_t baseV = (size_t)bh * DKH * SEQ;
  int q0 = qtile * 128 + wave * 32;

  bf16x8 aQ[2][2];
#pragma unroll
  for (int qf = 0; qf < 2; ++qf)
#pragma unroll
    for (int dh = 0; dh < 2; ++dh)
      aQ[qf][dh] = *reinterpret_cast<const bf16x8*>(
          Qb + baseQK + (size_t)(q0 + qf * 16 + l15) * DKH + dh * 32 + g * 8);

  float m[2] = {-1e30f, -1e30f}, lsum[2] = {0.f, 0.f};
  f32x4 accO[2][4];  // accO[qf][dt][r] = O[q=l15][d=dt*16+g*4+r]
#pragma unroll
  for (int qf = 0; qf < 2; ++qf)
#pragma unroll
    for (int dt = 0; dt < 4; ++dt) accO[qf][dt] = (f32x4){0.f, 0.f, 0.f, 0.f};

  // streaming pointers: one for K (4KB/chunk), one for V (4KB/chunk)
  const unsigned short* kp = Kb + baseQK + (size_t)l15 * DKH + g * 8;
  const unsigned short* vp = VtC + baseV + l15 * 32 + g * 4;

  bf16x8 kA[2][2], kB[2][2];
  bf16x4 vb[2][4];      // vb[tt][dt]
  bf16x4 pf[2][2];      // pf[qf][tt]

#define ISSUE_K(buf)                                  \
  do {                                                \
    GLOAD16(buf[0][0], kp, 0);                        \
    GLOAD16(buf[0][1], kp, 64);                       \
    GLOAD16(buf[1][0], kp, 2048);                     \
    GLOAD16(buf[1][1], kp, 2112);                     \
    kp += 2048;                                       \
  } while (0)
#define ISSUE_V()                                     \
  do {                                                \
    GLOAD8(vb[0][0], vp, 0);                          \
    GLOAD8(vb[1][0], vp, 32);                         \
    GLOAD8(vb[0][1], vp, 1024);                       \
    GLOAD8(vb[1][1], vp, 1056);                       \
    GLOAD8(vb[0][2], vp, 2048);                       \
    GLOAD8(vb[1][2], vp, 2080);                       \
    GLOAD8(vb[0][3], vp, 3072);                       \
    GLOAD8(vb[1][3], vp, 3104);                       \
    vp += 2048;                                       \
  } while (0)

  auto qksm = [&](const bf16x8 (&kf)[2][2]) {
    f32x4 sc[2][2];
#pragma unroll
    for (int qf = 0; qf < 2; ++qf)
#pragma unroll
      for (int tt = 0; tt < 2; ++tt) {
        f32x4 z = (f32x4){0.f, 0.f, 0.f, 0.f};
#pragma unroll
        for (int dh = 0; dh < 2; ++dh)
          z = __builtin_amdgcn_mfma_f32_16x16x32_bf16(kf[tt][dh], aQ[qf][dh], z, 0, 0, 0);
        sc[qf][tt] = z;
      }
#pragma unroll
    for (int qf = 0; qf < 2; ++qf) {
      // lane-local max over this lane's 8 scores of row q=l15
      float lm = fmaxf(
          fmaxf(fmaxf(sc[qf][0][0], sc[qf][0][1]), fmaxf(sc[qf][0][2], sc[qf][0][3])),
          fmaxf(fmaxf(sc[qf][1][0], sc[qf][1][1]), fmaxf(sc[qf][1][2], sc[qf][1][3])));
      if (__any(lm > m[qf] + 8.f)) {  // rare: true row-max reduce + rescale
        float vm = lm;
        vm = fmaxf(vm, __shfl_xor(vm, 16));
        vm = fmaxf(vm, __shfl_xor(vm, 32));
        float mnew = fmaxf(m[qf], vm);
        float alpha = __builtin_amdgcn_exp2f(m[qf] - mnew);
        m[qf] = mnew;
        lsum[qf] *= alpha;
#pragma unroll
        for (int dt = 0; dt < 4; ++dt)
#pragma unroll
          for (int r = 0; r < 4; ++r) accO[qf][dt][r] *= alpha;  // lane-local!
      }
      float pv[8];
#pragma unroll
      for (int tt = 0; tt < 2; ++tt)
#pragma unroll
        for (int r = 0; r < 4; ++r)
          pv[tt * 4 + r] = __builtin_amdgcn_exp2f(sc[qf][tt][r] - m[qf]);
      lsum[qf] +=
          ((pv[0] + pv[1]) + (pv[2] + pv[3])) + ((pv[4] + pv[5]) + (pv[6] + pv[7]));
#pragma unroll
      for (int tt = 0; tt < 2; ++tt) {
        unsigned w0, w1;
        asm("v_cvt_pk_bf16_f32 %0, %1, %2"
            : "=v"(w0) : "v"(pv[tt * 4 + 0]), "v"(pv[tt * 4 + 1]));
        asm("v_cvt_pk_bf16_f32 %0, %1, %2"
            : "=v"(w1) : "v"(pv[tt * 4 + 2]), "v"(pv[tt * 4 + 3]));
        union { unsigned u[2]; bf16x4 v; } pk;
        pk.u[0] = w0; pk.u[1] = w1;
        pf[qf][tt] = pk.v;
      }
    }
  };

  auto pvstep = [&]() {
#pragma unroll
    for (int qf = 0; qf < 2; ++qf)
#pragma unroll
      for (int tt = 0; tt < 2; ++tt)
#pragma unroll
        for (int dt = 0; dt < 4; ++dt)
          mfma16x16x16(accO[qf][dt], vb[tt][dt], pf[qf][tt]);
  };

  const int NT = SEQ / 32;  // 64 chunks
  ISSUE_K(kA);
  for (int pc = 0; pc < NT; pc += 2) {
    // chunk pc (kA current)
    ISSUE_V();
    ISSUE_K(kB);
    WAITV(12);   // kA resident (oldest 4 of {kA, V, kB})
    qksm(kA);
    WAITV(4);    // V resident (kB still in flight)
    pvstep();
    // chunk pc+1 (kB current)
    ISSUE_V();
    if (pc + 2 < NT) {
      ISSUE_K(kA);
      WAITV(12);  // kB resident
    } else {
      WAITV(8);   // kB resident (no kA issued)
    }
    qksm(kB);
    if (pc + 2 < NT) {
      WAITV(4);
    } else {
      WAITV(0);
    }
    pvstep();
  }
#undef ISSUE_K
#undef ISSUE_V

  int b_ = bh >> 4, h_ = bh & 15;
#pragma unroll
  for (int qf = 0; qf < 2; ++qf) {
    float ls = lsum[qf];
    ls += __shfl_xor(ls, 16);
    ls += __shfl_xor(ls, 32);
    float inv = 1.f / ls;   // row q = l15: lane-local
    int sq = q0 + qf * 16 + l15;
#pragma unroll
    for (int dt = 0; dt < 4; ++dt)
#pragma unroll
      for (int r = 0; r < 4; ++r) {
        float val = accO[qf][dt][r] * inv;
        AO[(size_t)(b_ * SEQ + sq) * DM + h_ * DKH + dt * 16 + g * 4 + r] = f2bf(val);
      }
  }
}

extern "C" void kernel_launch(void* const* d_in, const int* in_sizes, int n_in,
                              void* d_out, int out_size, void* d_ws, size_t ws_size,
                              hipStream_t stream) {
  (void)in_sizes; (void)n_in; (void)out_size; (void)ws_size;
  const float* queries = (const float*)d_in[0];
  const float* keys = (const float*)d_in[1];
  const float* values = (const float*)d_in[2];
  const float* Wq = (const float*)d_in[3];
  const float* bq = (const float*)d_in[4];
  const float* Wk = (const float*)d_in[5];
  const float* bk = (const float*)d_in[6];
  const float* Wv = (const float*)d_in[7];
  const float* bv = (const float*)d_in[8];
  const float* Wo = (const float*)d_in[9];
  const float* bo = (const float*)d_in[10];
  float* out = (float*)d_out;

  char* ws = (char*)d_ws;
  unsigned short* wt_q = (unsigned short*)(ws + 0 * (1u << 21));
  unsigned short* wt_k = (unsigned short*)(ws + 1 * (1u << 21));
  unsigned short* wt_v = (unsigned short*)(ws + 2 * (1u << 21));
  unsigned short* wt_o = (unsigned short*)(ws + 3 * (1u << 21));
  unsigned short* Qb = (unsigned short*)(ws + (8u << 20));
  unsigned short* Kb = (unsigned short*)(ws + (24u << 20));
  unsigned short* Vt = (unsigned short*)(ws + (40u << 20));
  unsigned short* AO = (unsigned short*)(ws + (56u << 20));
  // total ws use: 72 MiB

  dim3 tgrid(32, 32);
  wcast_t<<<tgrid, 256, 0, stream>>>(Wq, wt_q);
  wcast_t<<<tgrid, 256, 0, stream>>>(Wk, wt_k);
  wcast_t<<<tgrid, 256, 0, stream>>>(Wv, wt_v);
  wcast_t<<<tgrid, 256, 0, stream>>>(Wo, wt_o);

  const float SQ = 0.125f * 1.4426950408889634f;  // fold 1/sqrt(64) and log2(e) into Q
  gemm128<0, 0><<<512, 256, 0, stream>>>(queries, wt_q, bq, Qb, SQ);
  gemm128<0, 0><<<512, 256, 0, stream>>>(keys, wt_k, bk, Kb, 1.0f);
  gemm128<1, 0><<<512, 256, 0, stream>>>(values, wt_v, bv, Vt, 1.0f);
  attn_fwd<<<1024, 256, 0, stream>>>(Qb, Kb, Vt, AO);
  gemm128<2, 1><<<512, 256, 0, stream>>>(AO, wt_o, bo, out, 1.0f);
}